// Round 19
// baseline (208.206 us; speedup 1.0000x reference)
//
#include <hip/hip_runtime.h>
#include <hip/hip_bf16.h>

#define DEV __device__ __forceinline__

typedef __attribute__((ext_vector_type(4))) float  f32x4;
typedef __attribute__((ext_vector_type(8))) short  s16x8;
typedef __attribute__((ext_vector_type(8))) __bf16 bf16x8;

// problem constants
#define NQ   1025
#define BH   64        // B*H
#define NPAD 1152      // padded per-(b,h) row count (18*64 = 9*128)
#define MT   65600     // BH*NQ rows in tail
#define DFF  1024

DEV short f2bf(float f){
  unsigned u = __builtin_bit_cast(unsigned, f);
  u = u + 0x7fffu + ((u >> 16) & 1u);   // RNE
  return (short)(u >> 16);
}
DEV float bf2f(short s){
  unsigned u = ((unsigned)(unsigned short)s) << 16;
  return __builtin_bit_cast(float, u);
}
DEV f32x4 zero4(){ f32x4 z; z[0]=0.f; z[1]=0.f; z[2]=0.f; z[3]=0.f; return z; }
DEV s16x8 zero8(){ s16x8 z; for(int e=0;e<8;e++) z[e]=0; return z; }

DEV f32x4 mfma16(s16x8 a, s16x8 b, f32x4 c){
  return __builtin_amdgcn_mfma_f32_16x16x32_bf16(
      __builtin_bit_cast(bf16x8, a), __builtin_bit_cast(bf16x8, b), c, 0, 0, 0);
}

// async global->LDS, 16B per lane; LDS dest wave-uniform base + lane*16
DEV void gll16(const void* g, void* l){
  __builtin_amdgcn_global_load_lds((const __attribute__((address_space(1))) void*)g,
                                   (__attribute__((address_space(3))) void*)l, 16, 0, 0);
}

// LDS tiles: [rows][64] bf16, row stride 128 B, XOR swizzle on byte bits 4..6
DEV s16x8 lds_frag(const char* base, int row, int k8){
  int byte = row*128 + k8*2; byte ^= (row & 7) << 4;
  return *(const s16x8*)(base + byte);
}
DEV void lds_write16(char* base, int row, int k8, s16x8 v){
  int byte = row*128 + k8*2; byte ^= (row & 7) << 4;
  *(s16x8*)(base + byte) = v;
}
DEV void lds_write2(char* base, int row, int col, short v){
  int byte = row*128 + col*2; byte ^= (row & 7) << 4;
  *(short*)(base + byte) = v;
}
// 256 B row stride variants (128-col bf16 tiles)
DEV void lds_w16_256(char* base, int row, int col, s16x8 v){
  int byte = row*256 + col*2; byte ^= (row & 7) << 4;
  *(s16x8*)(base + byte) = v;
}
DEV s16x8 lds_r16_256(const char* base, int row, int col){
  int byte = row*256 + col*2; byte ^= (row & 7) << 4;
  return *(const s16x8*)(base + byte);
}
DEV void lds_w2_256(char* base, int row, int col, short v){
  int byte = row*256 + col*2; byte ^= (row & 7) << 4;
  *(short*)(base + byte) = v;
}
// blob image write (same layout as lds tiles)
DEV void blob_w16(char* blob, int row, int k8, s16x8 v){
  int byte = row*128 + k8*2; byte ^= (row & 7) << 4;
  *(s16x8*)(blob + byte) = v;
}

// ---------- fused prep (r18-verified): cvtA | cvtW | cvtV | cvtFB ----------
__global__ __launch_bounds__(256)
void k_prep(const float* __restrict__ q, const float* __restrict__ kk,
            const float* __restrict__ v, const float* __restrict__ w_qk,
            const float* __restrict__ fw1, const float* __restrict__ fw2,
            char* __restrict__ ab, char* __restrict__ wb,
            char* __restrict__ vb, char* __restrict__ f1B, char* __restrict__ f2B){
  __shared__ float SMF[64*129];
  int bid = blockIdx.x;
  int tid = threadIdx.x;
  if (bid < 1152){
    int mt = bid>>4, kt = bid&15;
    int r = tid>>1, ks = (tid&1)*32;
    int pr = mt*128 + r;
    int part = pr >= 4608;
    int pp = part ? pr-4608 : pr;
    int b = pp/NPAD, i = pp%NPAD;
    const float* src = nullptr;
    if (!part && i < 1025) src = q  + ((long)(b*1025+i))*1024 + kt*64 + ks;
    if ( part && i < 1024) src = kk + ((long)(b*1024+i))*1024 + kt*64 + ks;
    char* blob = ab + ((long)(mt*16+kt))*16384;
    #pragma unroll
    for (int c8=0;c8<32;c8+=8){
      s16x8 vv = zero8();
      if (src){
        f32x4 f0 = *(const f32x4*)(src + c8);
        f32x4 f1 = *(const f32x4*)(src + c8 + 4);
        #pragma unroll
        for(int e=0;e<4;e++){ vv[e]=f2bf(f0[e]); vv[4+e]=f2bf(f1[e]); }
      }
      blob_w16(blob, r, ks+c8, vv);
    }
  } else if (bid < 1280){
    int loc = bid - 1152;
    int nt = loc>>4, kt = loc&15;
    float (*T)[129] = (float(*)[129])SMF;
    for (int idx=tid; idx<8192; idx+=256){
      int kr = idx>>7, nc = idx&127;
      T[kr][nc] = w_qk[(long)(kt*64+kr)*1024 + nt*128+nc];
    }
    __syncthreads();
    int r = tid>>1, ks=(tid&1)*32;
    char* blob = wb + ((long)(nt*16+kt))*16384;
    #pragma unroll
    for (int c8=0;c8<32;c8+=8){
      s16x8 vv;
      #pragma unroll
      for(int e=0;e<8;e++) vv[e] = f2bf(T[ks+c8+e][r]);
      blob_w16(blob, r, ks+c8, vv);
    }
  } else if (bid < 2304){
    int loc = bid - 1280;
    int jt = loc&15, bh = loc>>4;
    int b = bh>>4, h = bh&15;
    float (*T)[65] = (float(*)[65])SMF;
    for (int idx=tid; idx<4096; idx+=256){
      int jr = idx>>6, cc = idx&63;
      int j = jt*64+jr;
      T[jr][cc] = (j<1024)? v[((long)(b*1024+j))*1024 + h*64+cc] : 0.f;
    }
    __syncthreads();
    int r = tid>>2, js=(tid&3)*16;
    char* blob = vb + ((long)(bh*18+jt))*8192;
    #pragma unroll
    for (int c8=0;c8<16;c8+=8){
      s16x8 vv;
      #pragma unroll
      for(int e=0;e<8;e++) vv[e] = f2bf(T[js+c8+e][r]);
      blob_w16(blob, r, js+c8, vv);
    }
  } else {
    int loc = bid - 2304;
    int d = loc&15, which = loc>>4;
    float (*T)[65] = (float(*)[65])SMF;
    for (int idx=tid; idx<4096; idx+=256){
      int r = idx>>6, c = idx&63;
      T[r][c] = (which==0) ? fw1[(long)r*DFF + d*64 + c]
                           : fw2[(long)(d*64+r)*64 + c];
    }
    __syncthreads();
    char* blob = (which==0 ? f1B : f2B) + (long)d*8192;
    int rr = tid>>2, js = (tid&3)*16;
    #pragma unroll
    for (int c8=0;c8<16;c8+=8){
      s16x8 vv;
      #pragma unroll
      for(int e=0;e<8;e++) vv[e] = f2bf(T[js+c8+e][rr]);
      blob_w16(blob, rr, js+c8, vv);
    }
  }
}

// ---------- projection GEMM (r18-verified) ----------
__global__ __launch_bounds__(256,2)
void k_proj(const char* __restrict__ ab, const char* __restrict__ wb,
            char* __restrict__ qpB, char* __restrict__ kpB,
            float* __restrict__ qnorm, float* __restrict__ knorm){
  __shared__ char SM[32768];
  char* A = SM; char* Bm = SM+16384;
  int flat = blockIdx.x;                 // 576
  int g = (flat&7)*72 + (flat>>3);       // XCD-contiguous
  int mt = g>>3, nt = g&7;
  int tid=threadIdx.x, lane=tid&63, wv=tid>>6, lr=lane&15, lg=lane>>4;
  f32x4 acc[4][4];
  for(int a=0;a<4;a++) for(int b=0;b<4;b++) acc[a][b]=zero4();
  int wm=(wv>>1)*64, wn=(wv&1)*64;
  for (int kt=0; kt<16; kt++){
    const char* asrc = ab + ((long)(mt*16+kt))*16384 + wv*4096 + lane*16;
    const char* bsrc = wb + ((long)(nt*16+kt))*16384 + wv*4096 + lane*16;
    char* adst = A + wv*4096;  char* bdst = Bm + wv*4096;
    #pragma unroll
    for (int t=0;t<4;t++){
      gll16(asrc + t*1024, adst + t*1024);
      gll16(bsrc + t*1024, bdst + t*1024);
    }
    __syncthreads();
    #pragma unroll
    for (int kc=0;kc<64;kc+=32){
      int lk = kc + (lg<<3);
      s16x8 af[4], bfr[4];
      #pragma unroll
      for(int i=0;i<4;i++) af[i]  = lds_frag(A,  wm + i*16 + lr, lk);
      #pragma unroll
      for(int i=0;i<4;i++) bfr[i] = lds_frag(Bm, wn + i*16 + lr, lk);
      #pragma unroll
      for(int mi=0;mi<4;mi++)
        #pragma unroll
        for(int ni=0;ni<4;ni++) acc[mi][ni] = mfma16(af[mi], bfr[ni], acc[mi][ni]);
    }
    __syncthreads();
  }
  int head = nt*2 + (wv&1);
  #pragma unroll
  for(int mi=0;mi<4;mi++)
  #pragma unroll
  for(int j=0;j<4;j++){
    float ss = 0.f;
    #pragma unroll
    for(int ni=0;ni<4;ni++){ float x=acc[mi][ni][j]; ss += x*x; }
    ss += __shfl_xor(ss,1); ss += __shfl_xor(ss,2);
    ss += __shfl_xor(ss,4); ss += __shfl_xor(ss,8);
    if (lr==0){
      int pr = mt*128 + wm + mi*16 + lg*4 + j;
      int part = pr>=4608; int pp = part? pr-4608:pr;
      int b = pp/NPAD, i = pp%NPAD;
      float scv = 1.f/fmaxf(sqrtf(ss), 1e-12f);
      (part? knorm : qnorm)[(b*16+head)*NPAD + i] = scv;
    }
  }
  #pragma unroll
  for(int mi=0;mi<4;mi++)
  #pragma unroll
  for(int ni=0;ni<4;ni++)
  #pragma unroll
  for(int j=0;j<4;j++)
    lds_w2_256(SM, wm+mi*16+lg*4+j, wn+ni*16+lr, f2bf(acc[mi][ni][j]));
  __syncthreads();
  {
    int r = tid>>1, half = tid&1;
    int pr = mt*128 + r;
    int part = pr>=4608; int pp = part? pr-4608:pr;
    int b = pp/NPAD, i = pp%NPAD;
    int h2 = nt*2 + half;
    char* dst = (part? kpB : qpB) + ((long)((b*16+h2)*18 + (i>>6)))*8192;
    int rr = i&63;
    #pragma unroll
    for (int c8=0;c8<64;c8+=8){
      s16x8 vv = lds_r16_256(SM, r, half*64 + c8);
      blob_w16(dst, rr, c8, vv);
    }
  }
}

// ---------- attention (r16/r18-verified): dead-chunk cut, jt loops 0..15 ----------
__global__ __launch_bounds__(256,2)
void k_attn(const char* __restrict__ qpB, const char* __restrict__ kpB,
            const char* __restrict__ vtB,
            const float* __restrict__ qnorm, const float* __restrict__ knorm,
            short* __restrict__ att){
  __shared__ char SM[49152];
  char* Q = SM; char* KT = SM+16384; char* VT = KT+8192; char* P = VT+8192;
  int flat = blockIdx.x;                 // 576
  int g = (flat&7)*72 + (flat>>3);
  int bh = g/9, it = g%9;
  int i0 = it*128;
  int tid=threadIdx.x, lane=tid&63, wv=tid>>6, lr=lane&15, lg=lane>>4;
  {
    const char* src = qpB + ((long)(bh*18 + it*2))*8192 + wv*4096 + lane*16;
    char* dst = Q + wv*4096;
    #pragma unroll
    for (int t=0;t<4;t++) gll16(src + t*1024, dst + t*1024);
  }
  float rq[2][4];
  #pragma unroll
  for(int mi=0;mi<2;mi++)
  #pragma unroll
  for(int j=0;j<4;j++)
    rq[mi][j] = qnorm[bh*NPAD + i0 + wv*32+mi*16+lg*4+j];
  f32x4 oacc[2][4];
  for(int a=0;a<2;a++) for(int b=0;b<4;b++) oacc[a][b]=zero4();
  for (int jt=0; jt<16; ++jt){
    {
      const char* ks = kpB + ((long)(bh*18+jt))*8192 + wv*2048 + lane*16;
      const char* vs = vtB + ((long)(bh*18+jt))*8192 + wv*2048 + lane*16;
      gll16(ks,      KT + wv*2048);
      gll16(ks+1024, KT + wv*2048 + 1024);
      gll16(vs,      VT + wv*2048);
      gll16(vs+1024, VT + wv*2048 + 1024);
    }
    float rk[4];
    #pragma unroll
    for(int ni=0;ni<4;ni++) rk[ni] = knorm[bh*NPAD + jt*64 + ni*16+lr];
    __syncthreads();
    f32x4 sc[2][4];
    for(int a=0;a<2;a++) for(int b=0;b<4;b++) sc[a][b]=zero4();
    #pragma unroll
    for(int kc=0;kc<64;kc+=32){
      int lk = kc + (lg<<3);
      s16x8 af[2], bfr[4];
      #pragma unroll
      for(int i=0;i<2;i++) af[i]=lds_frag(Q, wv*32 + i*16 + lr, lk);
      #pragma unroll
      for(int i=0;i<4;i++) bfr[i]=lds_frag(KT, i*16 + lr, lk);
      #pragma unroll
      for(int mi=0;mi<2;mi++)
        #pragma unroll
        for(int ni=0;ni<4;ni++) sc[mi][ni]=mfma16(af[mi],bfr[ni],sc[mi][ni]);
    }
    #pragma unroll
    for(int mi=0;mi<2;mi++)
    #pragma unroll
    for(int ni=0;ni<4;ni++)
    #pragma unroll
    for(int j=0;j<4;j++){
      float x = sc[mi][ni][j] * rq[mi][j] * rk[ni];
      x = x>0.f?x:0.f;
      lds_write2(P, wv*32 + mi*16 + lg*4 + j, ni*16 + lr, f2bf(x));
    }
    __syncthreads();
    #pragma unroll
    for(int kc=0;kc<64;kc+=32){
      int lk = kc + (lg<<3);
      s16x8 pf[2], vf[4];
      #pragma unroll
      for(int i=0;i<2;i++) pf[i]=lds_frag(P, wv*32 + i*16 + lr, lk);
      #pragma unroll
      for(int i=0;i<4;i++) vf[i]=lds_frag(VT, i*16 + lr, lk);
      #pragma unroll
      for(int mi=0;mi<2;mi++)
        #pragma unroll
        for(int ni=0;ni<4;ni++) oacc[mi][ni]=mfma16(pf[mi],vf[ni],oacc[mi][ni]);
    }
    __syncthreads();
  }
  char* OS = SM+16384;
  #pragma unroll
  for(int mi=0;mi<2;mi++)
  #pragma unroll
  for(int ni=0;ni<4;ni++)
  #pragma unroll
  for(int j=0;j<4;j++)
    lds_write2(OS, wv*32+mi*16+lg*4+j, ni*16+lr, f2bf(oacc[mi][ni][j]));
  __syncthreads();
  {
    int r = tid>>1, half = tid&1;
    int i = i0 + r;
    if (i < 1025){
      short* dst = att + ((long)bh*1025 + i)*64 + half*32;
      #pragma unroll
      for (int u=0; u<32; u+=8){
        s16x8 vv = lds_frag(OS, r, half*32 + u);
        *(s16x8*)(dst + u) = vv;
      }
    }
  }
}

// ---------- tail-pre (round-9 verified): 512 threads = 8 waves x 16 rows ----------
__global__ __launch_bounds__(512,4)
void k_tailpre(const short* __restrict__ att, const float* __restrict__ q,
    const float* __restrict__ w1, const float* __restrict__ b1,
    const float* __restrict__ w2, const float* __restrict__ b2,
    const float* __restrict__ w3, const float* __restrict__ b3,
    float* __restrict__ tf){
  __shared__ char SM[73728];
  char* R1 = SM;            // X1 -> o12
  char* R2 = SM + 16384;    // X2
  char* R3 = SM + 32768;    // RH
  char* WA = SM + 49152;    // w1T [32][64]
  char* WB = SM + 53248;    // w2T [32][64]
  char* W3 = SM + 57344;    // w3T [64][128] 256-stride
  long m0 = (long)blockIdx.x*128;
  int tid=threadIdx.x, lane=tid&63, wv=tid>>6, lr=lane&15, lg=lane>>4;
  int wr0 = wv*16;
  for (int idx=tid; idx<2048; idx+=512){
    int n=idx>>6, c=idx&63;
    lds_write2(WA, n, c, f2bf(w1[c*32+n]));
    lds_write2(WB, n, c, f2bf(w2[c*32+n]));
  }
  for (int idx=tid; idx<8192; idx+=512){
    int n=idx>>7, kx=idx&127;
    lds_w2_256(W3, n, kx, f2bf(w3[kx*64+n]));
  }
  {
    int r = tid>>2, ks=(tid&3)*16;
    long m = m0 + r;
    if (m < MT){
      int bh=(int)(m/1025); int i=(int)(m-(long)bh*1025); int b=bh>>4, h=bh&15;
      const short* asrc = att + m*64 + ks;
      const float* qsrc = q + ((long)b*1025+i)*1024 + h*64 + ks;
      #pragma unroll
      for (int c8=0;c8<16;c8+=8){
        s16x8 av = *(const s16x8*)(asrc + c8);
        f32x4 q0 = *(const f32x4*)(qsrc + c8);
        f32x4 q1 = *(const f32x4*)(qsrc + c8 + 4);
        s16x8 x1v,x2v,rhv;
        #pragma unroll
        for(int e=0;e<4;e++){
          float o0=bf2f(av[e]),   r0=q0[e];
          float o1=bf2f(av[4+e]), r1=q1[e];
          x1v[e]=f2bf(o0*r0);   x1v[4+e]=f2bf(o1*r1);
          x2v[e]=f2bf(r0-o0);   x2v[4+e]=f2bf(r1-o1);
          rhv[e]=f2bf(r0);      rhv[4+e]=f2bf(r1);
        }
        lds_write16(R1, r, ks+c8, x1v);
        lds_write16(R2, r, ks+c8, x2v);
        lds_write16(R3, r, ks+c8, rhv);
      }
    } else {
      s16x8 z = zero8();
      #pragma unroll
      for (int c8=0;c8<16;c8+=8){
        lds_write16(R1, r, ks+c8, z);
        lds_write16(R2, r, ks+c8, z);
        lds_write16(R3, r, ks+c8, z);
      }
    }
  }
  __syncthreads();
  f32x4 a1[4];
  #pragma unroll
  for(int ni=0;ni<4;ni++) a1[ni]=zero4();
  #pragma unroll
  for (int kc=0;kc<64;kc+=32){
    int lk = kc + (lg<<3);
    s16x8 af1 = lds_frag(R1, wr0+lr, lk);
    s16x8 af2 = lds_frag(R2, wr0+lr, lk);
    s16x8 bw1[2], bw2[2];
    #pragma unroll
    for(int i=0;i<2;i++){
      bw1[i]=lds_frag(WA, i*16+lr, lk);
      bw2[i]=lds_frag(WB, i*16+lr, lk);
    }
    #pragma unroll
    for(int ni=0;ni<2;ni++){
      a1[ni]   = mfma16(af1, bw1[ni], a1[ni]);
      a1[2+ni] = mfma16(af2, bw2[ni], a1[2+ni]);
    }
  }
  float bias12[4];
  #pragma unroll
  for(int ni=0;ni<4;ni++){ int cc=ni*16+lr; bias12[ni] = (cc<32)? b1[cc] : b2[cc-32]; }
  #pragma unroll
  for(int ni=0;ni<4;ni++)
  #pragma unroll
  for(int j=0;j<4;j++){
    float x = a1[ni][j] + bias12[ni];
    x = x>0.f?x:0.f;
    lds_write2(R1, wr0+lg*4+j, ni*16+lr, f2bf(x));
  }
  f32x4 a2[4];
  #pragma unroll
  for(int ni=0;ni<4;ni++) a2[ni]=zero4();
  #pragma unroll
  for (int kc=0;kc<64;kc+=32){
    int lk = kc + (lg<<3);
    s16x8 ao = lds_frag(R1, wr0+lr, lk);
    s16x8 ar = lds_frag(R3, wr0+lr, lk);
    s16x8 bo[4], br[4];
    #pragma unroll
    for(int i=0;i<4;i++){
      bo[i]=lds_r16_256(W3, i*16+lr, lk);
      br[i]=lds_r16_256(W3, i*16+lr, 64+lk);
    }
    #pragma unroll
    for(int ni=0;ni<4;ni++){
      a2[ni]=mfma16(ao, bo[ni], a2[ni]);
      a2[ni]=mfma16(ar, br[ni], a2[ni]);
    }
  }
  float b3v[4];
  #pragma unroll
  for(int ni=0;ni<4;ni++) b3v[ni] = b3[ni*16+lr];
  #pragma unroll
  for(int j=0;j<4;j++){
    long m = m0 + wr0 + lg*4 + j;
    if (m < MT){
      int bh=(int)(m/1025); int i=(int)(m-(long)bh*1025); int b=bh>>4, h=bh&15;
      const float* qsrc = q + ((long)b*1025+i)*1024 + h*64;
      #pragma unroll
      for(int ni=0;ni<4;ni++){
        int cc = ni*16+lr;
        tf[m*64+cc] = a2[ni][j] + b3v[ni] + qsrc[cc];
      }
    }
  }
}

// ---------- FFN v11: ZERO barriers, per-wave private weight staging ----------
// 64-row blocks x 128 threads (2 waves x 32 rows; data path verified r13).
// Each wave stages its OWN W1/W2 chunk via gll16 and drains with in-wave
// s_waitcnt vmcnt(0) (+sched_barrier to pin the dependent ds_reads).
// LDS 48 KB: T 8K | U 8K | 2 waves x 16K private weights. 3 blocks/CU, grid 1025.
__global__ __launch_bounds__(128,2)
void k_ffn(const float* __restrict__ tf,
      const char* __restrict__ f1B, const char* __restrict__ f2B,
      const float* __restrict__ fb1, const float* __restrict__ fb2,
      const float* __restrict__ ln_g, const float* __restrict__ ln_b,
      const float* __restrict__ v, float* __restrict__ out){
  __shared__ char SM[49152];
  char* T  = SM;             // [64][64] bf16 t
  char* U  = SM + 8192;      // [64][64] bf16 u
  long m0 = (long)blockIdx.x*64;
  int tid=threadIdx.x, lane=tid&63, wv=tid>>6, lr=lane&15, lg=lane>>4;
  char* W1 = SM + 16384 + wv*16384;       // per-wave 8 KB
  char* W2 = W1 + 8192;                   // per-wave 8 KB
  // stage T from tf (fp32 -> bf16): r = tid>>1 in 0..63, wave-private rows (r13-verified)
  {
    int r=tid>>1, ks=(tid&1)*32; long m=m0+r;
    #pragma unroll
    for(int c8=0;c8<32;c8+=8){
      s16x8 vv = zero8();
      if (m<MT){
        f32x4 f0 = *(const f32x4*)(tf + m*64 + ks + c8);
        f32x4 f1 = *(const f32x4*)(tf + m*64 + ks + c8 + 4);
        #pragma unroll
        for(int e=0;e<4;e++){ vv[e]=f2bf(f0[e]); vv[4+e]=f2bf(f1[e]); }
      }
      lds_write16(T, r, ks+c8, vv);
    }
  }
  f32x4 acc2[2][4];
  for(int a=0;a<2;a++) for(int b=0;b<4;b++) acc2[a][b]=zero4();
  for (int d=0; d<16; ++d){
    { // this wave stages the full 8 KB W1 chunk + 8 KB W2 chunk for itself
      const char* s1 = f1B + (long)d*8192 + lane*16;
      const char* s2 = f2B + (long)d*8192 + lane*16;
      #pragma unroll
      for (int t=0;t<8;t++){
        gll16(s1 + t*1024, W1 + t*1024);
        gll16(s2 + t*1024, W2 + t*1024);
      }
    }
    // in-wave drain of own staging; fence stops hipcc hoisting the ds_reads above it
    asm volatile("s_waitcnt vmcnt(0)" ::: "memory");
    __builtin_amdgcn_sched_barrier(0);
    // GEMM1: u = relu(T @ W1c + fb1)  (rows wv*32.. — identical r10/r13 inner code)
    f32x4 sc[2][4];
    for(int a=0;a<2;a++) for(int b=0;b<4;b++) sc[a][b]=zero4();
    #pragma unroll
    for(int kc=0;kc<64;kc+=32){
      int lk = kc + (lg<<3);
      s16x8 af[2], bfr[4];
      #pragma unroll
      for(int i=0;i<2;i++) af[i]=lds_frag(T, wv*32+i*16+lr, lk);
      #pragma unroll
      for(int i=0;i<4;i++) bfr[i]=lds_frag(W1, i*16+lr, lk);
      #pragma unroll
      for(int mi=0;mi<2;mi++)
        #pragma unroll
        for(int ni=0;ni<4;ni++) sc[mi][ni]=mfma16(af[mi],bfr[ni],sc[mi][ni]);
    }
    #pragma unroll
    for(int mi=0;mi<2;mi++)
    #pragma unroll
    for(int ni=0;ni<4;ni++)
    #pragma unroll
    for(int j=0;j<4;j++){
      int uc = ni*16+lr;
      float x = sc[mi][ni][j] + fb1[d*64+uc];
      x = x>0.f?x:0.f;
      lds_write2(U, wv*32+mi*16+lg*4+j, uc, f2bf(x));
    }
    // U wave-private: in-wave RAW (verified r10/r13) -> no barrier
    #pragma unroll
    for(int kc=0;kc<64;kc+=32){
      int lk = kc + (lg<<3);
      s16x8 uf[2], wf[4];
      #pragma unroll
      for(int i=0;i<2;i++) uf[i]=lds_frag(U, wv*32+i*16+lr, lk);
      #pragma unroll
      for(int i=0;i<4;i++) wf[i]=lds_frag(W2, i*16+lr, lk);
      #pragma unroll
      for(int mi=0;mi<2;mi++)
        #pragma unroll
        for(int ni=0;ni<4;ni++) acc2[mi][ni]=mfma16(uf[mi],wf[ni],acc2[mi][ni]);
    }
    // no end-of-chunk barrier: next staging overwrites only THIS wave's buffers,
    // and all reads of them (above) complete before the next gll16 issues (in-wave order)
  }
  // epilogue: x = acc2 + fb2 + t ; LN(64) ; + vh ; write out (r13-verified mapping)
  #pragma unroll
  for(int mi=0;mi<2;mi++){
    float xv[4][4];
    long mbase = m0 + wv*32 + mi*16 + lg*4;
    #pragma unroll
    for(int ni=0;ni<4;ni++)
    #pragma unroll
    for(int j=0;j<4;j++){
      long m = mbase + j;
      int c = ni*16+lr;
      float t = (m<MT)? tf[m*64+c] : 0.f;
      xv[ni][j] = acc2[mi][ni][j] + fb2[c] + t;
    }
    #pragma unroll
    for(int j=0;j<4;j++){
      float s = xv[0][j]+xv[1][j]+xv[2][j]+xv[3][j];
      #pragma unroll
      for(int mm=1;mm<16;mm<<=1) s += __shfl_xor(s, mm);
      float mu = s*(1.f/64.f);
      float vs = 0.f;
      #pragma unroll
      for(int ni=0;ni<4;ni++){ float d2=xv[ni][j]-mu; vs += d2*d2; }
      #pragma unroll
      for(int mm=1;mm<16;mm<<=1) vs += __shfl_xor(vs, mm);
      float inv = rsqrtf(vs*(1.f/64.f) + 1e-5f);
      long m = mbase + j;
      if (m < MT){
        int bh = (int)(m/1025); int i = (int)(m - (long)bh*1025);
        int b = bh>>4, h = bh&15;
        #pragma unroll
        for(int ni=0;ni<4;ni++){
          int c = ni*16+lr;
          float y = (xv[ni][j]-mu)*inv*ln_g[c] + ln_b[c];
          float vh = (i<1024)? v[((long)b*1024 + i)*1024 + h*64 + c] : 0.f;
          out[((long)b*1025 + i)*1024 + h*64 + c] = y + vh;
        }
      }
    }
  }
}

extern "C" void kernel_launch(void* const* d_in, const int* in_sizes, int n_in,
                              void* d_out, int out_size, void* d_ws, size_t ws_size,
                              hipStream_t stream) {
  const float* q    = (const float*)d_in[0];
  const float* k    = (const float*)d_in[1];
  const float* v    = (const float*)d_in[2];
  const float* w_qk = (const float*)d_in[3];
  const float* w1   = (const float*)d_in[5];
  const float* b1   = (const float*)d_in[6];
  const float* w2   = (const float*)d_in[7];
  const float* b2   = (const float*)d_in[8];
  const float* w3   = (const float*)d_in[9];
  const float* b3   = (const float*)d_in[10];
  const float* fw1  = (const float*)d_in[11];
  const float* fb1  = (const float*)d_in[12];
  const float* fw2  = (const float*)d_in[13];
  const float* fb2  = (const float*)d_in[14];
  const float* ln_g = (const float*)d_in[15];
  const float* ln_b = (const float*)d_in[16];
  float* out = (float*)d_out;

  char* ws = (char*)d_ws;
  const size_t OFF_A   = 0;
  const size_t SZ_A    = 25190400;
  const size_t OFF_WB  = OFF_A + SZ_A;
  const size_t OFF_F1B = OFF_WB  + (size_t)8*16*16384;          // 2 MB
  const size_t OFF_F2B = OFF_F1B + (size_t)16*8192;             // 128 KB
  const size_t OFF_VT  = OFF_F2B + (size_t)16*8192;             // 128 KB
  const size_t OFF_QP  = OFF_VT  + (size_t)64*18*8192;
  const size_t OFF_KP  = OFF_QP  + (size_t)64*18*8192;
  const size_t OFF_QN  = OFF_KP  + (size_t)64*18*8192;
  const size_t OFF_KN  = OFF_QN  + (size_t)BH*NPAD*4;
  const size_t NEEDED  = OFF_KN  + (size_t)BH*NPAD*4;
  if (ws_size < NEEDED) return;

  char*  ab   = ws + OFF_A;
  short* att  = (short*)(ws + OFF_A);
  float* tf   = (float*)(ws + OFF_A + 8396800);
  char*  wb   = ws + OFF_WB;
  char*  f1B  = ws + OFF_F1B;
  char*  f2B  = ws + OFF_F2B;
  char*  vtB  = ws + OFF_VT;
  char*  qpB  = ws + OFF_QP;
  char*  kpB  = ws + OFF_KP;
  float* qnorm= (float*)(ws + OFF_QN);
  float* knorm= (float*)(ws + OFF_KN);

  k_prep<<<2336, 256, 0, stream>>>(q, k, v, w_qk, fw1, fw2, ab, wb, vtB, f1B, f2B);
  k_proj<<<576, 256, 0, stream>>>(ab, wb, qpB, kpB, qnorm, knorm);
  k_attn<<<576, 256, 0, stream>>>(qpB, kpB, vtB, qnorm, knorm, att);
  k_tailpre<<<513, 512, 0, stream>>>(att, q, w1, b1, w2, b2, w3, b3, tf);
  k_ffn<<<1025, 128, 0, stream>>>(tf, f1B, f2B, fb1, fb2, ln_g, ln_b, v, out);
}

// Round 20
// 179.484 us; speedup vs baseline: 1.1600x; 1.1600x over previous
//
#include <hip/hip_runtime.h>
#include <hip/hip_bf16.h>

#define DEV __device__ __forceinline__

typedef __attribute__((ext_vector_type(4))) float  f32x4;
typedef __attribute__((ext_vector_type(8))) short  s16x8;
typedef __attribute__((ext_vector_type(8))) __bf16 bf16x8;

// problem constants
#define NQ   1025
#define BH   64        // B*H
#define NPAD 1152      // padded per-(b,h) row count (18*64 = 9*128)
#define MT   65600     // BH*NQ rows in tail
#define DFF  1024

DEV short f2bf(float f){
  unsigned u = __builtin_bit_cast(unsigned, f);
  u = u + 0x7fffu + ((u >> 16) & 1u);   // RNE
  return (short)(u >> 16);
}
DEV float bf2f(short s){
  unsigned u = ((unsigned)(unsigned short)s) << 16;
  return __builtin_bit_cast(float, u);
}
DEV f32x4 zero4(){ f32x4 z; z[0]=0.f; z[1]=0.f; z[2]=0.f; z[3]=0.f; return z; }
DEV s16x8 zero8(){ s16x8 z; for(int e=0;e<8;e++) z[e]=0; return z; }

DEV f32x4 mfma16(s16x8 a, s16x8 b, f32x4 c){
  return __builtin_amdgcn_mfma_f32_16x16x32_bf16(
      __builtin_bit_cast(bf16x8, a), __builtin_bit_cast(bf16x8, b), c, 0, 0, 0);
}

// async global->LDS, 16B per lane; LDS dest wave-uniform base + lane*16
DEV void gll16(const void* g, void* l){
  __builtin_amdgcn_global_load_lds((const __attribute__((address_space(1))) void*)g,
                                   (__attribute__((address_space(3))) void*)l, 16, 0, 0);
}

// LDS tiles: [rows][64] bf16, row stride 128 B, XOR swizzle on byte bits 4..6
DEV s16x8 lds_frag(const char* base, int row, int k8){
  int byte = row*128 + k8*2; byte ^= (row & 7) << 4;
  return *(const s16x8*)(base + byte);
}
DEV void lds_write16(char* base, int row, int k8, s16x8 v){
  int byte = row*128 + k8*2; byte ^= (row & 7) << 4;
  *(s16x8*)(base + byte) = v;
}
DEV void lds_write2(char* base, int row, int col, short v){
  int byte = row*128 + col*2; byte ^= (row & 7) << 4;
  *(short*)(base + byte) = v;
}
// 256 B row stride variants (128-col bf16 tiles)
DEV void lds_w16_256(char* base, int row, int col, s16x8 v){
  int byte = row*256 + col*2; byte ^= (row & 7) << 4;
  *(s16x8*)(base + byte) = v;
}
DEV s16x8 lds_r16_256(const char* base, int row, int col){
  int byte = row*256 + col*2; byte ^= (row & 7) << 4;
  return *(const s16x8*)(base + byte);
}
DEV void lds_w2_256(char* base, int row, int col, short v){
  int byte = row*256 + col*2; byte ^= (row & 7) << 4;
  *(short*)(base + byte) = v;
}
// blob image write (same layout as lds tiles)
DEV void blob_w16(char* blob, int row, int k8, s16x8 v){
  int byte = row*128 + k8*2; byte ^= (row & 7) << 4;
  *(s16x8*)(blob + byte) = v;
}

// ---------- fused prep (r18-verified): cvtA | cvtW | cvtV | cvtFB ----------
__global__ __launch_bounds__(256)
void k_prep(const float* __restrict__ q, const float* __restrict__ kk,
            const float* __restrict__ v, const float* __restrict__ w_qk,
            const float* __restrict__ fw1, const float* __restrict__ fw2,
            char* __restrict__ ab, char* __restrict__ wb,
            char* __restrict__ vb, char* __restrict__ f1B, char* __restrict__ f2B){
  __shared__ float SMF[64*129];
  int bid = blockIdx.x;
  int tid = threadIdx.x;
  if (bid < 1152){
    int mt = bid>>4, kt = bid&15;
    int r = tid>>1, ks = (tid&1)*32;
    int pr = mt*128 + r;
    int part = pr >= 4608;
    int pp = part ? pr-4608 : pr;
    int b = pp/NPAD, i = pp%NPAD;
    const float* src = nullptr;
    if (!part && i < 1025) src = q  + ((long)(b*1025+i))*1024 + kt*64 + ks;
    if ( part && i < 1024) src = kk + ((long)(b*1024+i))*1024 + kt*64 + ks;
    char* blob = ab + ((long)(mt*16+kt))*16384;
    #pragma unroll
    for (int c8=0;c8<32;c8+=8){
      s16x8 vv = zero8();
      if (src){
        f32x4 f0 = *(const f32x4*)(src + c8);
        f32x4 f1 = *(const f32x4*)(src + c8 + 4);
        #pragma unroll
        for(int e=0;e<4;e++){ vv[e]=f2bf(f0[e]); vv[4+e]=f2bf(f1[e]); }
      }
      blob_w16(blob, r, ks+c8, vv);
    }
  } else if (bid < 1280){
    int loc = bid - 1152;
    int nt = loc>>4, kt = loc&15;
    float (*T)[129] = (float(*)[129])SMF;
    for (int idx=tid; idx<8192; idx+=256){
      int kr = idx>>7, nc = idx&127;
      T[kr][nc] = w_qk[(long)(kt*64+kr)*1024 + nt*128+nc];
    }
    __syncthreads();
    int r = tid>>1, ks=(tid&1)*32;
    char* blob = wb + ((long)(nt*16+kt))*16384;
    #pragma unroll
    for (int c8=0;c8<32;c8+=8){
      s16x8 vv;
      #pragma unroll
      for(int e=0;e<8;e++) vv[e] = f2bf(T[ks+c8+e][r]);
      blob_w16(blob, r, ks+c8, vv);
    }
  } else if (bid < 2304){
    int loc = bid - 1280;
    int jt = loc&15, bh = loc>>4;
    int b = bh>>4, h = bh&15;
    float (*T)[65] = (float(*)[65])SMF;
    for (int idx=tid; idx<4096; idx+=256){
      int jr = idx>>6, cc = idx&63;
      int j = jt*64+jr;
      T[jr][cc] = (j<1024)? v[((long)(b*1024+j))*1024 + h*64+cc] : 0.f;
    }
    __syncthreads();
    int r = tid>>2, js=(tid&3)*16;
    char* blob = vb + ((long)(bh*18+jt))*8192;
    #pragma unroll
    for (int c8=0;c8<16;c8+=8){
      s16x8 vv;
      #pragma unroll
      for(int e=0;e<8;e++) vv[e] = f2bf(T[js+c8+e][r]);
      blob_w16(blob, r, js+c8, vv);
    }
  } else {
    int loc = bid - 2304;
    int d = loc&15, which = loc>>4;
    float (*T)[65] = (float(*)[65])SMF;
    for (int idx=tid; idx<4096; idx+=256){
      int r = idx>>6, c = idx&63;
      T[r][c] = (which==0) ? fw1[(long)r*DFF + d*64 + c]
                           : fw2[(long)(d*64+r)*64 + c];
    }
    __syncthreads();
    char* blob = (which==0 ? f1B : f2B) + (long)d*8192;
    int rr = tid>>2, js = (tid&3)*16;
    #pragma unroll
    for (int c8=0;c8<16;c8+=8){
      s16x8 vv;
      #pragma unroll
      for(int e=0;e<8;e++) vv[e] = f2bf(T[js+c8+e][rr]);
      blob_w16(blob, rr, js+c8, vv);
    }
  }
}

// ---------- projection GEMM (r18-verified) ----------
__global__ __launch_bounds__(256,2)
void k_proj(const char* __restrict__ ab, const char* __restrict__ wb,
            char* __restrict__ qpB, char* __restrict__ kpB,
            float* __restrict__ qnorm, float* __restrict__ knorm){
  __shared__ char SM[32768];
  char* A = SM; char* Bm = SM+16384;
  int flat = blockIdx.x;                 // 576
  int g = (flat&7)*72 + (flat>>3);       // XCD-contiguous
  int mt = g>>3, nt = g&7;
  int tid=threadIdx.x, lane=tid&63, wv=tid>>6, lr=lane&15, lg=lane>>4;
  f32x4 acc[4][4];
  for(int a=0;a<4;a++) for(int b=0;b<4;b++) acc[a][b]=zero4();
  int wm=(wv>>1)*64, wn=(wv&1)*64;
  for (int kt=0; kt<16; kt++){
    const char* asrc = ab + ((long)(mt*16+kt))*16384 + wv*4096 + lane*16;
    const char* bsrc = wb + ((long)(nt*16+kt))*16384 + wv*4096 + lane*16;
    char* adst = A + wv*4096;  char* bdst = Bm + wv*4096;
    #pragma unroll
    for (int t=0;t<4;t++){
      gll16(asrc + t*1024, adst + t*1024);
      gll16(bsrc + t*1024, bdst + t*1024);
    }
    __syncthreads();
    #pragma unroll
    for (int kc=0;kc<64;kc+=32){
      int lk = kc + (lg<<3);
      s16x8 af[4], bfr[4];
      #pragma unroll
      for(int i=0;i<4;i++) af[i]  = lds_frag(A,  wm + i*16 + lr, lk);
      #pragma unroll
      for(int i=0;i<4;i++) bfr[i] = lds_frag(Bm, wn + i*16 + lr, lk);
      #pragma unroll
      for(int mi=0;mi<4;mi++)
        #pragma unroll
        for(int ni=0;ni<4;ni++) acc[mi][ni] = mfma16(af[mi], bfr[ni], acc[mi][ni]);
    }
    __syncthreads();
  }
  int head = nt*2 + (wv&1);
  #pragma unroll
  for(int mi=0;mi<4;mi++)
  #pragma unroll
  for(int j=0;j<4;j++){
    float ss = 0.f;
    #pragma unroll
    for(int ni=0;ni<4;ni++){ float x=acc[mi][ni][j]; ss += x*x; }
    ss += __shfl_xor(ss,1); ss += __shfl_xor(ss,2);
    ss += __shfl_xor(ss,4); ss += __shfl_xor(ss,8);
    if (lr==0){
      int pr = mt*128 + wm + mi*16 + lg*4 + j;
      int part = pr>=4608; int pp = part? pr-4608:pr;
      int b = pp/NPAD, i = pp%NPAD;
      float scv = 1.f/fmaxf(sqrtf(ss), 1e-12f);
      (part? knorm : qnorm)[(b*16+head)*NPAD + i] = scv;
    }
  }
  #pragma unroll
  for(int mi=0;mi<4;mi++)
  #pragma unroll
  for(int ni=0;ni<4;ni++)
  #pragma unroll
  for(int j=0;j<4;j++)
    lds_w2_256(SM, wm+mi*16+lg*4+j, wn+ni*16+lr, f2bf(acc[mi][ni][j]));
  __syncthreads();
  {
    int r = tid>>1, half = tid&1;
    int pr = mt*128 + r;
    int part = pr>=4608; int pp = part? pr-4608:pr;
    int b = pp/NPAD, i = pp%NPAD;
    int h2 = nt*2 + half;
    char* dst = (part? kpB : qpB) + ((long)((b*16+h2)*18 + (i>>6)))*8192;
    int rr = i&63;
    #pragma unroll
    for (int c8=0;c8<64;c8+=8){
      s16x8 vv = lds_r16_256(SM, r, half*64 + c8);
      blob_w16(dst, rr, c8, vv);
    }
  }
}

// ---------- attention (r16/r18-verified): dead-chunk cut, jt loops 0..15 ----------
__global__ __launch_bounds__(256,2)
void k_attn(const char* __restrict__ qpB, const char* __restrict__ kpB,
            const char* __restrict__ vtB,
            const float* __restrict__ qnorm, const float* __restrict__ knorm,
            short* __restrict__ att){
  __shared__ char SM[49152];
  char* Q = SM; char* KT = SM+16384; char* VT = KT+8192; char* P = VT+8192;
  int flat = blockIdx.x;                 // 576
  int g = (flat&7)*72 + (flat>>3);
  int bh = g/9, it = g%9;
  int i0 = it*128;
  int tid=threadIdx.x, lane=tid&63, wv=tid>>6, lr=lane&15, lg=lane>>4;
  {
    const char* src = qpB + ((long)(bh*18 + it*2))*8192 + wv*4096 + lane*16;
    char* dst = Q + wv*4096;
    #pragma unroll
    for (int t=0;t<4;t++) gll16(src + t*1024, dst + t*1024);
  }
  float rq[2][4];
  #pragma unroll
  for(int mi=0;mi<2;mi++)
  #pragma unroll
  for(int j=0;j<4;j++)
    rq[mi][j] = qnorm[bh*NPAD + i0 + wv*32+mi*16+lg*4+j];
  f32x4 oacc[2][4];
  for(int a=0;a<2;a++) for(int b=0;b<4;b++) oacc[a][b]=zero4();
  for (int jt=0; jt<16; ++jt){
    {
      const char* ks = kpB + ((long)(bh*18+jt))*8192 + wv*2048 + lane*16;
      const char* vs = vtB + ((long)(bh*18+jt))*8192 + wv*2048 + lane*16;
      gll16(ks,      KT + wv*2048);
      gll16(ks+1024, KT + wv*2048 + 1024);
      gll16(vs,      VT + wv*2048);
      gll16(vs+1024, VT + wv*2048 + 1024);
    }
    float rk[4];
    #pragma unroll
    for(int ni=0;ni<4;ni++) rk[ni] = knorm[bh*NPAD + jt*64 + ni*16+lr];
    __syncthreads();
    f32x4 sc[2][4];
    for(int a=0;a<2;a++) for(int b=0;b<4;b++) sc[a][b]=zero4();
    #pragma unroll
    for(int kc=0;kc<64;kc+=32){
      int lk = kc + (lg<<3);
      s16x8 af[2], bfr[4];
      #pragma unroll
      for(int i=0;i<2;i++) af[i]=lds_frag(Q, wv*32 + i*16 + lr, lk);
      #pragma unroll
      for(int i=0;i<4;i++) bfr[i]=lds_frag(KT, i*16 + lr, lk);
      #pragma unroll
      for(int mi=0;mi<2;mi++)
        #pragma unroll
        for(int ni=0;ni<4;ni++) sc[mi][ni]=mfma16(af[mi],bfr[ni],sc[mi][ni]);
    }
    #pragma unroll
    for(int mi=0;mi<2;mi++)
    #pragma unroll
    for(int ni=0;ni<4;ni++)
    #pragma unroll
    for(int j=0;j<4;j++){
      float x = sc[mi][ni][j] * rq[mi][j] * rk[ni];
      x = x>0.f?x:0.f;
      lds_write2(P, wv*32 + mi*16 + lg*4 + j, ni*16 + lr, f2bf(x));
    }
    __syncthreads();
    #pragma unroll
    for(int kc=0;kc<64;kc+=32){
      int lk = kc + (lg<<3);
      s16x8 pf[2], vf[4];
      #pragma unroll
      for(int i=0;i<2;i++) pf[i]=lds_frag(P, wv*32 + i*16 + lr, lk);
      #pragma unroll
      for(int i=0;i<4;i++) vf[i]=lds_frag(VT, i*16 + lr, lk);
      #pragma unroll
      for(int mi=0;mi<2;mi++)
        #pragma unroll
        for(int ni=0;ni<4;ni++) oacc[mi][ni]=mfma16(pf[mi],vf[ni],oacc[mi][ni]);
    }
    __syncthreads();
  }
  char* OS = SM+16384;
  #pragma unroll
  for(int mi=0;mi<2;mi++)
  #pragma unroll
  for(int ni=0;ni<4;ni++)
  #pragma unroll
  for(int j=0;j<4;j++)
    lds_write2(OS, wv*32+mi*16+lg*4+j, ni*16+lr, f2bf(oacc[mi][ni][j]));
  __syncthreads();
  {
    int r = tid>>1, half = tid&1;
    int i = i0 + r;
    if (i < 1025){
      short* dst = att + ((long)bh*1025 + i)*64 + half*32;
      #pragma unroll
      for (int u=0; u<32; u+=8){
        s16x8 vv = lds_frag(OS, r, half*32 + u);
        *(s16x8*)(dst + u) = vv;
      }
    }
  }
}

// ---------- tail-pre (round-9 verified): 512 threads = 8 waves x 16 rows ----------
__global__ __launch_bounds__(512,4)
void k_tailpre(const short* __restrict__ att, const float* __restrict__ q,
    const float* __restrict__ w1, const float* __restrict__ b1,
    const float* __restrict__ w2, const float* __restrict__ b2,
    const float* __restrict__ w3, const float* __restrict__ b3,
    float* __restrict__ tf){
  __shared__ char SM[73728];
  char* R1 = SM;            // X1 -> o12
  char* R2 = SM + 16384;    // X2
  char* R3 = SM + 32768;    // RH
  char* WA = SM + 49152;    // w1T [32][64]
  char* WB = SM + 53248;    // w2T [32][64]
  char* W3 = SM + 57344;    // w3T [64][128] 256-stride
  long m0 = (long)blockIdx.x*128;
  int tid=threadIdx.x, lane=tid&63, wv=tid>>6, lr=lane&15, lg=lane>>4;
  int wr0 = wv*16;
  for (int idx=tid; idx<2048; idx+=512){
    int n=idx>>6, c=idx&63;
    lds_write2(WA, n, c, f2bf(w1[c*32+n]));
    lds_write2(WB, n, c, f2bf(w2[c*32+n]));
  }
  for (int idx=tid; idx<8192; idx+=512){
    int n=idx>>7, kx=idx&127;
    lds_w2_256(W3, n, kx, f2bf(w3[kx*64+n]));
  }
  {
    int r = tid>>2, ks=(tid&3)*16;
    long m = m0 + r;
    if (m < MT){
      int bh=(int)(m/1025); int i=(int)(m-(long)bh*1025); int b=bh>>4, h=bh&15;
      const short* asrc = att + m*64 + ks;
      const float* qsrc = q + ((long)b*1025+i)*1024 + h*64 + ks;
      #pragma unroll
      for (int c8=0;c8<16;c8+=8){
        s16x8 av = *(const s16x8*)(asrc + c8);
        f32x4 q0 = *(const f32x4*)(qsrc + c8);
        f32x4 q1 = *(const f32x4*)(qsrc + c8 + 4);
        s16x8 x1v,x2v,rhv;
        #pragma unroll
        for(int e=0;e<4;e++){
          float o0=bf2f(av[e]),   r0=q0[e];
          float o1=bf2f(av[4+e]), r1=q1[e];
          x1v[e]=f2bf(o0*r0);   x1v[4+e]=f2bf(o1*r1);
          x2v[e]=f2bf(r0-o0);   x2v[4+e]=f2bf(r1-o1);
          rhv[e]=f2bf(r0);      rhv[4+e]=f2bf(r1);
        }
        lds_write16(R1, r, ks+c8, x1v);
        lds_write16(R2, r, ks+c8, x2v);
        lds_write16(R3, r, ks+c8, rhv);
      }
    } else {
      s16x8 z = zero8();
      #pragma unroll
      for (int c8=0;c8<16;c8+=8){
        lds_write16(R1, r, ks+c8, z);
        lds_write16(R2, r, ks+c8, z);
        lds_write16(R3, r, ks+c8, z);
      }
    }
  }
  __syncthreads();
  f32x4 a1[4];
  #pragma unroll
  for(int ni=0;ni<4;ni++) a1[ni]=zero4();
  #pragma unroll
  for (int kc=0;kc<64;kc+=32){
    int lk = kc + (lg<<3);
    s16x8 af1 = lds_frag(R1, wr0+lr, lk);
    s16x8 af2 = lds_frag(R2, wr0+lr, lk);
    s16x8 bw1[2], bw2[2];
    #pragma unroll
    for(int i=0;i<2;i++){
      bw1[i]=lds_frag(WA, i*16+lr, lk);
      bw2[i]=lds_frag(WB, i*16+lr, lk);
    }
    #pragma unroll
    for(int ni=0;ni<2;ni++){
      a1[ni]   = mfma16(af1, bw1[ni], a1[ni]);
      a1[2+ni] = mfma16(af2, bw2[ni], a1[2+ni]);
    }
  }
  float bias12[4];
  #pragma unroll
  for(int ni=0;ni<4;ni++){ int cc=ni*16+lr; bias12[ni] = (cc<32)? b1[cc] : b2[cc-32]; }
  #pragma unroll
  for(int ni=0;ni<4;ni++)
  #pragma unroll
  for(int j=0;j<4;j++){
    float x = a1[ni][j] + bias12[ni];
    x = x>0.f?x:0.f;
    lds_write2(R1, wr0+lg*4+j, ni*16+lr, f2bf(x));
  }
  f32x4 a2[4];
  #pragma unroll
  for(int ni=0;ni<4;ni++) a2[ni]=zero4();
  #pragma unroll
  for (int kc=0;kc<64;kc+=32){
    int lk = kc + (lg<<3);
    s16x8 ao = lds_frag(R1, wr0+lr, lk);
    s16x8 ar = lds_frag(R3, wr0+lr, lk);
    s16x8 bo[4], br[4];
    #pragma unroll
    for(int i=0;i<4;i++){
      bo[i]=lds_r16_256(W3, i*16+lr, lk);
      br[i]=lds_r16_256(W3, i*16+lr, 64+lk);
    }
    #pragma unroll
    for(int ni=0;ni<4;ni++){
      a2[ni]=mfma16(ao, bo[ni], a2[ni]);
      a2[ni]=mfma16(ar, br[ni], a2[ni]);
    }
  }
  float b3v[4];
  #pragma unroll
  for(int ni=0;ni<4;ni++) b3v[ni] = b3[ni*16+lr];
  #pragma unroll
  for(int j=0;j<4;j++){
    long m = m0 + wr0 + lg*4 + j;
    if (m < MT){
      int bh=(int)(m/1025); int i=(int)(m-(long)bh*1025); int b=bh>>4, h=bh&15;
      const float* qsrc = q + ((long)b*1025+i)*1024 + h*64;
      #pragma unroll
      for(int ni=0;ni<4;ni++){
        int cc = ni*16+lr;
        tf[m*64+cc] = a2[ni][j] + b3v[ni] + qsrc[cc];
      }
    }
  }
}

// ---------- FFN (r10/r16/r18-verified 59us): 256 thr, 4 waves x 32 rows, chunk staging ----------
__global__ __launch_bounds__(256,3)
void k_ffn(const float* __restrict__ tf,
      const char* __restrict__ f1B, const char* __restrict__ f2B,
      const float* __restrict__ fb1, const float* __restrict__ fb2,
      const float* __restrict__ ln_g, const float* __restrict__ ln_b,
      const float* __restrict__ v, float* __restrict__ out){
  __shared__ char SM[49152];
  char* T  = SM;             // [128][64] bf16 t
  char* U  = SM + 16384;     // [128][64] bf16 u
  char* W1 = SM + 32768;     // [64][64] chunk
  char* W2 = SM + 40960;     // [64][64] chunk
  long m0 = (long)blockIdx.x*128;
  int tid=threadIdx.x, lane=tid&63, wv=tid>>6, lr=lane&15, lg=lane>>4;
  {
    int r=tid>>1, ks=(tid&1)*32; long m=m0+r;
    #pragma unroll
    for(int c8=0;c8<32;c8+=8){
      s16x8 vv = zero8();
      if (m<MT){
        f32x4 f0 = *(const f32x4*)(tf + m*64 + ks + c8);
        f32x4 f1 = *(const f32x4*)(tf + m*64 + ks + c8 + 4);
        #pragma unroll
        for(int e=0;e<4;e++){ vv[e]=f2bf(f0[e]); vv[4+e]=f2bf(f1[e]); }
      }
      lds_write16(T, r, ks+c8, vv);
    }
  }
  f32x4 acc2[2][4];
  for(int a=0;a<2;a++) for(int b=0;b<4;b++) acc2[a][b]=zero4();
  for (int d=0; d<16; ++d){
    { // stage chunk-d weights via global_load_lds (each wave: 2 KB of W1, 2 KB of W2)
      const char* s1 = f1B + (long)d*8192 + wv*2048 + lane*16;
      const char* s2 = f2B + (long)d*8192 + wv*2048 + lane*16;
      gll16(s1,        W1 + wv*2048);
      gll16(s1 + 1024, W1 + wv*2048 + 1024);
      gll16(s2,        W2 + wv*2048);
      gll16(s2 + 1024, W2 + wv*2048 + 1024);
    }
    __syncthreads();   // drains staging; also first-iter T-visibility
    f32x4 sc[2][4];
    for(int a=0;a<2;a++) for(int b=0;b<4;b++) sc[a][b]=zero4();
    #pragma unroll
    for(int kc=0;kc<64;kc+=32){
      int lk = kc + (lg<<3);
      s16x8 af[2], bfr[4];
      #pragma unroll
      for(int i=0;i<2;i++) af[i]=lds_frag(T, wv*32+i*16+lr, lk);
      #pragma unroll
      for(int i=0;i<4;i++) bfr[i]=lds_frag(W1, i*16+lr, lk);
      #pragma unroll
      for(int mi=0;mi<2;mi++)
        #pragma unroll
        for(int ni=0;ni<4;ni++) sc[mi][ni]=mfma16(af[mi],bfr[ni],sc[mi][ni]);
    }
    #pragma unroll
    for(int mi=0;mi<2;mi++)
    #pragma unroll
    for(int ni=0;ni<4;ni++)
    #pragma unroll
    for(int j=0;j<4;j++){
      int uc = ni*16+lr;
      float x = sc[mi][ni][j] + fb1[d*64+uc];
      x = x>0.f?x:0.f;
      lds_write2(U, wv*32+mi*16+lg*4+j, uc, f2bf(x));
    }
    // U wave-private: in-wave RAW -> no barrier
    #pragma unroll
    for(int kc=0;kc<64;kc+=32){
      int lk = kc + (lg<<3);
      s16x8 uf[2], wf[4];
      #pragma unroll
      for(int i=0;i<2;i++) uf[i]=lds_frag(U, wv*32+i*16+lr, lk);
      #pragma unroll
      for(int i=0;i<4;i++) wf[i]=lds_frag(W2, i*16+lr, lk);
      #pragma unroll
      for(int mi=0;mi<2;mi++)
        #pragma unroll
        for(int ni=0;ni<4;ni++) acc2[mi][ni]=mfma16(uf[mi],wf[ni],acc2[mi][ni]);
    }
    __syncthreads();   // all waves done with W1/W2 before next chunk's staging
  }
  #pragma unroll
  for(int mi=0;mi<2;mi++){
    float xv[4][4];
    long mbase = m0 + wv*32 + mi*16 + lg*4;
    #pragma unroll
    for(int ni=0;ni<4;ni++)
    #pragma unroll
    for(int j=0;j<4;j++){
      long m = mbase + j;
      int c = ni*16+lr;
      float t = (m<MT)? tf[m*64+c] : 0.f;
      xv[ni][j] = acc2[mi][ni][j] + fb2[c] + t;
    }
    #pragma unroll
    for(int j=0;j<4;j++){
      float s = xv[0][j]+xv[1][j]+xv[2][j]+xv[3][j];
      #pragma unroll
      for(int mm=1;mm<16;mm<<=1) s += __shfl_xor(s, mm);
      float mu = s*(1.f/64.f);
      float vs = 0.f;
      #pragma unroll
      for(int ni=0;ni<4;ni++){ float d2=xv[ni][j]-mu; vs += d2*d2; }
      #pragma unroll
      for(int mm=1;mm<16;mm<<=1) vs += __shfl_xor(vs, mm);
      float inv = rsqrtf(vs*(1.f/64.f) + 1e-5f);
      long m = mbase + j;
      if (m < MT){
        int bh = (int)(m/1025); int i = (int)(m - (long)bh*1025);
        int b = bh>>4, h = bh&15;
        #pragma unroll
        for(int ni=0;ni<4;ni++){
          int c = ni*16+lr;
          float y = (xv[ni][j]-mu)*inv*ln_g[c] + ln_b[c];
          float vh = (i<1024)? v[((long)b*1024 + i)*1024 + h*64 + c] : 0.f;
          out[((long)b*1025 + i)*1024 + h*64 + c] = y + vh;
        }
      }
    }
  }
}

extern "C" void kernel_launch(void* const* d_in, const int* in_sizes, int n_in,
                              void* d_out, int out_size, void* d_ws, size_t ws_size,
                              hipStream_t stream) {
  const float* q    = (const float*)d_in[0];
  const float* k    = (const float*)d_in[1];
  const float* v    = (const float*)d_in[2];
  const float* w_qk = (const float*)d_in[3];
  const float* w1   = (const float*)d_in[5];
  const float* b1   = (const float*)d_in[6];
  const float* w2   = (const float*)d_in[7];
  const float* b2   = (const float*)d_in[8];
  const float* w3   = (const float*)d_in[9];
  const float* b3   = (const float*)d_in[10];
  const float* fw1  = (const float*)d_in[11];
  const float* fb1  = (const float*)d_in[12];
  const float* fw2  = (const float*)d_in[13];
  const float* fb2  = (const float*)d_in[14];
  const float* ln_g = (const float*)d_in[15];
  const float* ln_b = (const float*)d_in[16];
  float* out = (float*)d_out;

  char* ws = (char*)d_ws;
  const size_t OFF_A   = 0;
  const size_t SZ_A    = 25190400;
  const size_t OFF_WB  = OFF_A + SZ_A;
  const size_t OFF_F1B = OFF_WB  + (size_t)8*16*16384;          // 2 MB
  const size_t OFF_F2B = OFF_F1B + (size_t)16*8192;             // 128 KB
  const size_t OFF_VT  = OFF_F2B + (size_t)16*8192;             // 128 KB
  const size_t OFF_QP  = OFF_VT  + (size_t)64*18*8192;
  const size_t OFF_KP  = OFF_QP  + (size_t)64*18*8192;
  const size_t OFF_QN  = OFF_KP  + (size_t)64*18*8192;
  const size_t OFF_KN  = OFF_QN  + (size_t)BH*NPAD*4;
  const size_t NEEDED  = OFF_KN  + (size_t)BH*NPAD*4;
  if (ws_size < NEEDED) return;

  char*  ab   = ws + OFF_A;
  short* att  = (short*)(ws + OFF_A);
  float* tf   = (float*)(ws + OFF_A + 8396800);
  char*  wb   = ws + OFF_WB;
  char*  f1B  = ws + OFF_F1B;
  char*  f2B  = ws + OFF_F2B;
  char*  vtB  = ws + OFF_VT;
  char*  qpB  = ws + OFF_QP;
  char*  kpB  = ws + OFF_KP;
  float* qnorm= (float*)(ws + OFF_QN);
  float* knorm= (float*)(ws + OFF_KN);

  k_prep<<<2336, 256, 0, stream>>>(q, k, v, w_qk, fw1, fw2, ab, wb, vtB, f1B, f2B);
  k_proj<<<576, 256, 0, stream>>>(ab, wb, qpB, kpB, qnorm, knorm);
  k_attn<<<576, 256, 0, stream>>>(qpB, kpB, vtB, qnorm, knorm, att);
  k_tailpre<<<513, 512, 0, stream>>>(att, q, w1, b1, w2, b2, w3, b3, tf);
  k_ffn<<<513, 256, 0, stream>>>(tf, f1B, f2B, fb1, fb2, ln_g, ln_b, v, out);
}